// Round 9
// baseline (13168.405 us; speedup 1.0000x reference)
//
#include <hip/hip_runtime.h>
#include <hip/hip_bf16.h>

#define TSTEPS 500
#define NB 512      // batch
#define FEAT 52
#define HID 128
#define G4 512      // 4*HID

// ---------- fast transcendentals (v_exp_f32 / v_rcp_f32), overflow-safe ----------
__device__ __forceinline__ float fexp2(float x) { return __builtin_amdgcn_exp2f(x); }
__device__ __forceinline__ float frcp(float x)  { return __builtin_amdgcn_rcpf(x); }
__device__ __forceinline__ float fsig(float x) {
  return frcp(1.0f + fexp2(-1.44269504088896341f * x));   // exact at +-inf
}
__device__ __forceinline__ float ftanh(float x) {
  float ax = fabsf(x);
  float e  = fexp2(2.88539008177792681f * ax);
  float r  = 1.0f - 2.0f * frcp(e + 1.0f);                // safe as e->inf
  return copysignf(r, x);
}

// ---------- storage-type helpers (fp32 or bf16 workspace) ----------
__device__ __forceinline__ float ldf(const float* p) { return *p; }
__device__ __forceinline__ float ldf(const __hip_bfloat16* p) { return __bfloat162float(*p); }
__device__ __forceinline__ void  stf(float* p, float v) { *p = v; }
__device__ __forceinline__ void  stf(__hip_bfloat16* p, float v) { *p = __float2bfloat16(v); }

// =====================================================================
// One-time transposes -> lane-coalesced weight loads everywhere.
// =====================================================================
__global__ __launch_bounds__(256)
void transpose_all_kernel(const float* __restrict__ wih2,
                          const float* __restrict__ wihf, const float* __restrict__ whhf,
                          const float* __restrict__ wihr, const float* __restrict__ whhr,
                          const float* __restrict__ whh2,
                          const float* __restrict__ W1,  const float* __restrict__ W2,
                          float* __restrict__ wT2,
                          float* __restrict__ wihTf, float* __restrict__ whhTf,
                          float* __restrict__ wihTr, float* __restrict__ whhTr,
                          float* __restrict__ whh2T,
                          float* __restrict__ W1T, float* __restrict__ W2T)
{
  const int b = blockIdx.x, tid = threadIdx.x;
  if (b < 512)        { int i=b*256+tid;        int r=i>>8,  c=i&255;  wT2  [c*G4 + r] = wih2[i]; }
  else if (b < 616)   { int i=(b-512)*256+tid;  int r=i/52,  c=i%52;   wihTf[c*G4 + r] = wihf[i]; }
  else if (b < 872)   { int i=(b-616)*256+tid;  int r=i>>7,  c=i&127;  whhTf[c*G4 + r] = whhf[i]; }
  else if (b < 976)   { int i=(b-872)*256+tid;  int r=i/52,  c=i%52;   wihTr[c*G4 + r] = wihr[i]; }
  else if (b < 1232)  { int i=(b-976)*256+tid;  int r=i>>7,  c=i&127;  whhTr[c*G4 + r] = whhr[i]; }
  else if (b < 1488)  { int i=(b-1232)*256+tid; int r=i>>7,  c=i&127;  whh2T[c*G4 + r] = whh2[i]; }
  else if (b < 1638)  { int i=(b-1488)*256+tid; int r=i>>7,  c=i&127;  W1T  [c*300 + r] = W1[i]; }
  else                { int i=(b-1638)*256+tid; if (i < 5400) { int r=i/300, c=i%300; W2T[c*18 + r] = W2[i]; } }
}

// =====================================================================
// Layer 1: bidirectional LSTM, persistent. 256 blocks (dir = bid>>7,
// 4 batch rows each), 512 threads. k-split 2-way across wave halves:
// kh=0 -> bias + x(52) + h[0..38), kh=1 -> h[38..128). 180 weight
// VGPRs/thread; (512,2) caps at 256 VGPR so the 8-wave block launches.
// Per-CU/step model: LDS 720 b128-broadcasts*4cyc ~= VALU 2880 cyc.
// =====================================================================
template<typename ST>
__global__ __launch_bounds__(512, 2)
void lstm1_kernel(const float* __restrict__ x,
                  const float* __restrict__ wihTf, const float* __restrict__ whhTf,
                  const float* __restrict__ bias_f,
                  const float* __restrict__ wihTr, const float* __restrict__ whhTr,
                  const float* __restrict__ bias_r,
                  ST* __restrict__ hs_f, ST* __restrict__ hs_r)
{
  const int tid = threadIdx.x;
  const int dir = blockIdx.x >> 7;
  const int b0  = (blockIdx.x & 127) * 4;
  const float* __restrict__ wihT = dir ? wihTr : wihTf;
  const float* __restrict__ whhT = dir ? whhTr : whhTf;
  const float* __restrict__ bias = dir ? bias_r : bias_f;
  ST* __restrict__ hs = dir ? hs_r : hs_f;

  const int p  = tid & 255;
  const int kh = tid >> 8;            // wave-uniform
  const int jA = p, jB = p + 256;

  __shared__ float hsh[HID][4];       // [k][b], rows 16B -> b128 broadcast
  __shared__ float xsh[FEAT][4];
  __shared__ float gshp[2][4][G4];    // [kh][b][gatecol] partial sums

  float wA[90], wB[90];
  if (kh == 0) {
    #pragma unroll
    for (int q = 0; q < 52; ++q) { wA[q]    = wihT[q*G4 + jA]; wB[q]    = wihT[q*G4 + jB]; }
    #pragma unroll
    for (int q = 0; q < 38; ++q) { wA[52+q] = whhT[q*G4 + jA]; wB[52+q] = whhT[q*G4 + jB]; }
  } else {
    #pragma unroll
    for (int q = 0; q < 90; ++q) { wA[q] = whhT[(38+q)*G4 + jA]; wB[q] = whhT[(38+q)*G4 + jB]; }
  }
  const float biasA = (kh == 0) ? bias[jA] : 0.f;
  const float biasB = (kh == 0) ? bias[jB] : 0.f;

  if (tid < HID) { *(float4*)&hsh[tid][0] = float4{0.f, 0.f, 0.f, 0.f}; }
  float c = 0.f;                       // cell state for (b=tid>>7, hid=tid&127)
  const int xb = tid & 3, xm = tid >> 2;
  if (tid < 4*FEAT) {
    const int t0 = dir ? (TSTEPS-1) : 0;
    xsh[xm][xb] = x[(b0+xb)*(TSTEPS*FEAT) + t0*FEAT + xm];
  }
  __syncthreads();

  #pragma unroll 1
  for (int t = 0; t < TSTEPS; ++t) {
    const int time = dir ? (TSTEPS-1-t) : t;
    float xpre = 0.f;                  // next-step x, hidden under dot phase
    if (tid < 4*FEAT && t+1 < TSTEPS) {
      const int tn = dir ? (TSTEPS-2-t) : (t+1);
      xpre = x[(b0+xb)*(TSTEPS*FEAT) + tn*FEAT + xm];
    }

    float aA0=biasA, aA1=biasA, aA2=biasA, aA3=biasA;
    float aB0=biasB, aB1=biasB, aB2=biasB, aB3=biasB;
    if (kh == 0) {
      #pragma unroll
      for (int m = 0; m < 52; ++m) {
        const float4 v = *(const float4*)&xsh[m][0];
        const float a = wA[m], bw = wB[m];
        aA0 += a*v.x;  aA1 += a*v.y;  aA2 += a*v.z;  aA3 += a*v.w;
        aB0 += bw*v.x; aB1 += bw*v.y; aB2 += bw*v.z; aB3 += bw*v.w;
      }
      #pragma unroll
      for (int k = 0; k < 38; ++k) {
        const float4 v = *(const float4*)&hsh[k][0];
        const float a = wA[52+k], bw = wB[52+k];
        aA0 += a*v.x;  aA1 += a*v.y;  aA2 += a*v.z;  aA3 += a*v.w;
        aB0 += bw*v.x; aB1 += bw*v.y; aB2 += bw*v.z; aB3 += bw*v.w;
      }
    } else {
      #pragma unroll
      for (int k = 0; k < 90; ++k) {
        const float4 v = *(const float4*)&hsh[38+k][0];
        const float a = wA[k], bw = wB[k];
        aA0 += a*v.x;  aA1 += a*v.y;  aA2 += a*v.z;  aA3 += a*v.w;
        aB0 += bw*v.x; aB1 += bw*v.y; aB2 += bw*v.z; aB3 += bw*v.w;
      }
    }
    gshp[kh][0][jA]=aA0; gshp[kh][1][jA]=aA1; gshp[kh][2][jA]=aA2; gshp[kh][3][jA]=aA3;
    gshp[kh][0][jB]=aB0; gshp[kh][1][jB]=aB1; gshp[kh][2][jB]=aB2; gshp[kh][3][jB]=aB3;
    __syncthreads();

    {  // epilogue: 512 states (4 b x 128 hid), bijective thread->state
      const int bb = tid >> 7, hid = tid & 127;
      const float gi = gshp[0][bb][hid]     + gshp[1][bb][hid];
      const float gf = gshp[0][bb][hid+128] + gshp[1][bb][hid+128];
      const float gg = gshp[0][bb][hid+256] + gshp[1][bb][hid+256];
      const float go = gshp[0][bb][hid+384] + gshp[1][bb][hid+384];
      c = fsig(gf)*c + fsig(gi)*ftanh(gg);
      const float h = fsig(go)*ftanh(c);
      hsh[hid][bb] = h;
      stf(&hs[(size_t)time*(NB*HID) + (size_t)(b0+bb)*HID + hid], h);
    }
    if (tid < 4*FEAT) xsh[xm][xb] = xpre;
    __syncthreads();
  }
}

// =====================================================================
// xp = [hs_f | hs_r] @ w_ih2^T + b2 for a time-chunk of nsteps.
// grid = nsteps*16 blocks. Tile 128x128, K-tiles 32, 8x8 micro, fp32 FMA.
// =====================================================================
template<typename ST1, typename ST2>
__global__ __launch_bounds__(256)
void xp2_gemm_kernel(const ST1* __restrict__ hs_f, const ST1* __restrict__ hs_r,
                     const float* __restrict__ wT2, const float* __restrict__ bias2,
                     ST2* __restrict__ xp)
{
  __shared__ float Ash[32][132];   // row stride 528B = 16B-aligned for b128
  __shared__ float Bsh[32][132];
  const int tid = threadIdx.x;
  const int mb = blockIdx.x >> 2, nb = blockIdx.x & 3;
  const int r0 = mb*128, j0 = nb*128;
  const int tm = tid >> 4, tn = tid & 15;
  const int m0 = tm*8,  n0 = tn*8;

  float acc[8][8];
  #pragma unroll
  for (int i = 0; i < 8; ++i)
    #pragma unroll
    for (int j = 0; j < 8; ++j) acc[i][j] = 0.f;

  #pragma unroll 1
  for (int kt = 0; kt < 8; ++kt) {
    const ST1* __restrict__ A = (kt < 4) ? hs_f : hs_r;
    const int ka = (kt & 3) * 32;
    #pragma unroll
    for (int e = 0; e < 16; ++e) {
      const int idx = tid + e*256;
      const int mm = idx >> 5, kk = idx & 31;
      Ash[kk][mm] = ldf(&A[(size_t)(r0+mm)*HID + ka + kk]);
    }
    const int k0 = kt*32;
    #pragma unroll
    for (int e = 0; e < 16; ++e) {
      const int idx = tid + e*256;
      const int kk = idx >> 7, jj = idx & 127;
      Bsh[kk][jj] = wT2[(k0+kk)*G4 + j0 + jj];
    }
    __syncthreads();
    #pragma unroll
    for (int kk = 0; kk < 32; ++kk) {
      float av[8], bv[8];
      *(float4*)&av[0] = *(const float4*)&Ash[kk][m0];
      *(float4*)&av[4] = *(const float4*)&Ash[kk][m0+4];
      *(float4*)&bv[0] = *(const float4*)&Bsh[kk][n0];
      *(float4*)&bv[4] = *(const float4*)&Bsh[kk][n0+4];
      #pragma unroll
      for (int i = 0; i < 8; ++i)
        #pragma unroll
        for (int j = 0; j < 8; ++j) acc[i][j] += av[i]*bv[j];
    }
    __syncthreads();
  }

  float bb[8];
  #pragma unroll
  for (int j = 0; j < 8; ++j) bb[j] = bias2[j0+n0+j];
  #pragma unroll
  for (int i = 0; i < 8; ++i) {
    const size_t base = (size_t)(r0+m0+i)*G4 + j0 + n0;
    #pragma unroll
    for (int j = 0; j < 8; ++j) stf(&xp[base + j], acc[i][j] + bb[j]);
  }
}

// =====================================================================
// Layer 2: unidirectional LSTM over a time-chunk of xp. 128 blocks
// (4 batch rows each), 512 threads, k-split 2-way. h,c carried across
// chunk launches via hcarry/ccarry (t0==0 -> zero init, carry unread,
// so 0xAA re-poison of ws is harmless).
// =====================================================================
template<typename ST2>
__global__ __launch_bounds__(512, 2)
void lstm2_kernel(const ST2* __restrict__ xp, const float* __restrict__ whh2T,
                  float* __restrict__ h2last,
                  float* __restrict__ hcarry, float* __restrict__ ccarry,
                  int t0, int nsteps)
{
  const int tid = threadIdx.x;
  const int b0  = blockIdx.x * 4;
  const int p = tid & 255, kh = tid >> 8;
  const int jA = p, jB = p + 256;
  __shared__ float hsh[HID][4];
  __shared__ float gshp[2][4][G4];

  float wA[64], wB[64];
  #pragma unroll
  for (int q = 0; q < 64; ++q) {
    wA[q] = whh2T[(kh*64+q)*G4 + jA];
    wB[q] = whh2T[(kh*64+q)*G4 + jB];
  }
  const int bb = tid >> 7, hid = tid & 127;
  float c;
  if (t0 == 0) {
    c = 0.f;
    hsh[hid][bb] = 0.f;
  } else {
    c = ccarry[(size_t)(b0+bb)*HID + hid];
    hsh[hid][bb] = hcarry[(size_t)(b0+bb)*HID + hid];
  }
  float cur[8];
  #pragma unroll
  for (int r = 0; r < 8; ++r) cur[r] = 0.f;
  if (kh == 0) {
    #pragma unroll
    for (int r = 0; r < 4; ++r) {
      cur[r]   = ldf(&xp[((size_t)(b0+r))*G4 + jA]);
      cur[4+r] = ldf(&xp[((size_t)(b0+r))*G4 + jB]);
    }
  }
  __syncthreads();

  #pragma unroll 1
  for (int t = 0; t < nsteps; ++t) {
    float nxt[8];
    #pragma unroll
    for (int r = 0; r < 8; ++r) nxt[r] = 0.f;
    if (kh == 0 && t+1 < nsteps) {
      const size_t rb = (size_t)(t+1)*NB + b0;
      #pragma unroll
      for (int r = 0; r < 4; ++r) {
        nxt[r]   = ldf(&xp[(rb+r)*G4 + jA]);
        nxt[4+r] = ldf(&xp[(rb+r)*G4 + jB]);
      }
    }
    float aA0=cur[0], aA1=cur[1], aA2=cur[2], aA3=cur[3];
    float aB0=cur[4], aB1=cur[5], aB2=cur[6], aB3=cur[7];
    const float* hb = &hsh[kh*64][0];
    #pragma unroll
    for (int q = 0; q < 64; ++q) {
      const float4 hv = *(const float4*)(hb + 4*q);
      const float a = wA[q], bw = wB[q];
      aA0 += a*hv.x;  aA1 += a*hv.y;  aA2 += a*hv.z;  aA3 += a*hv.w;
      aB0 += bw*hv.x; aB1 += bw*hv.y; aB2 += bw*hv.z; aB3 += bw*hv.w;
    }
    gshp[kh][0][jA]=aA0; gshp[kh][1][jA]=aA1; gshp[kh][2][jA]=aA2; gshp[kh][3][jA]=aA3;
    gshp[kh][0][jB]=aB0; gshp[kh][1][jB]=aB1; gshp[kh][2][jB]=aB2; gshp[kh][3][jB]=aB3;
    __syncthreads();
    {
      const float gi = gshp[0][bb][hid]     + gshp[1][bb][hid];
      const float gf = gshp[0][bb][hid+128] + gshp[1][bb][hid+128];
      const float gg = gshp[0][bb][hid+256] + gshp[1][bb][hid+256];
      const float go = gshp[0][bb][hid+384] + gshp[1][bb][hid+384];
      c = fsig(gf)*c + fsig(gi)*ftanh(gg);
      const float h = fsig(go)*ftanh(c);
      hsh[hid][bb] = h;
      if (t0 + t == TSTEPS-1) h2last[(size_t)(b0+bb)*HID + hid] = h;
      if (t == nsteps-1) {
        hcarry[(size_t)(b0+bb)*HID + hid] = h;
        ccarry[(size_t)(b0+bb)*HID + hid] = c;
      }
    }
    #pragma unroll
    for (int r = 0; r < 8; ++r) cur[r] = nxt[r];
    __syncthreads();
  }
}

// =====================================================================
// Head: selu(last @ W1^T + b1) @ W2^T + b2l -> softmax(18). One block/row.
// =====================================================================
__global__ __launch_bounds__(128)
void head_kernel(const float* __restrict__ h2last,
                 const float* __restrict__ W1T, const float* __restrict__ b1,
                 const float* __restrict__ W2T, const float* __restrict__ b2l,
                 float* __restrict__ out)
{
  const int r = blockIdx.x, tid = threadIdx.x;
  __shared__ float lsh[HID];
  __shared__ float zsh[304];
  __shared__ float lg[18];
  if (tid < HID) lsh[tid] = h2last[r*HID + tid];
  __syncthreads();
  for (int jj = tid; jj < 300; jj += 128) {
    float a = b1[jj];
    #pragma unroll 8
    for (int k = 0; k < HID; ++k) a += W1T[k*300 + jj] * lsh[k];
    const float lam = 1.0507009873554805f, alp = 1.6732632423543772f;
    zsh[jj] = a > 0.f ? lam * a : lam * alp * expm1f(a);
  }
  __syncthreads();
  if (tid < 18) {
    float a = b2l[tid];
    for (int k = 0; k < 300; ++k) a += W2T[k*18 + tid] * zsh[k];
    lg[tid] = a;
  }
  __syncthreads();
  if (tid < 18) {
    float mx = lg[0];
    #pragma unroll
    for (int k = 1; k < 18; ++k) mx = fmaxf(mx, lg[k]);
    float s = 0.f;
    #pragma unroll
    for (int k = 0; k < 18; ++k) s += expf(lg[k] - mx);
    out[r*18 + tid] = expf(lg[tid] - mx) / s;
  }
}

// =====================================================================
extern "C" void kernel_launch(void* const* d_in, const int* in_sizes, int n_in,
                              void* d_out, int out_size, void* d_ws, size_t ws_size,
                              hipStream_t stream)
{
  (void)in_sizes; (void)n_in; (void)out_size;
  const float* x     = (const float*)d_in[0];
  const float* wih_f = (const float*)d_in[1];
  const float* whh_f = (const float*)d_in[2];
  const float* b_f   = (const float*)d_in[3];
  const float* wih_r = (const float*)d_in[4];
  const float* whh_r = (const float*)d_in[5];
  const float* b_r   = (const float*)d_in[6];
  const float* wih2  = (const float*)d_in[7];
  const float* whh2  = (const float*)d_in[8];
  const float* b2    = (const float*)d_in[9];
  const float* W1    = (const float*)d_in[10];
  const float* b1    = (const float*)d_in[11];
  const float* W2    = (const float*)d_in[12];
  const float* b2l   = (const float*)d_in[13];
  float* out = (float*)d_out;

  // ---- fixed fp32 region: transposed weights + head/carry state ----
  float* fw = (float*)d_ws;
  float* wT2   = fw + 0;        // 131072
  float* wihTf = fw + 131072;   // 26624
  float* whhTf = fw + 157696;   // 65536
  float* wihTr = fw + 223232;   // 26624
  float* whhTr = fw + 249856;   // 65536
  float* whh2T = fw + 315392;   // 65536
  float* W1T   = fw + 380928;   // 38400
  float* W2T   = fw + 419328;   // 5400
  float* h2l   = fw + 424728;   // 65536
  float* hc    = fw + 490264;   // 65536
  float* cc    = fw + 555800;   // 65536
  const size_t baseF = 621336;                       // floats; *4 is 16B-aligned
  char* stbase = (char*)d_ws + baseF*4;

  const size_t nHS = (size_t)TSTEPS * NB * HID;      // 32,768,000
  const size_t nXP = (size_t)TSTEPS * NB * G4;       // 131,072,000

  transpose_all_kernel<<<1660, 256, 0, stream>>>(wih2, wih_f, whh_f, wih_r, whh_r, whh2,
                                                 W1, W2, wT2, wihTf, whhTf, wihTr, whhTr,
                                                 whh2T, W1T, W2T);

  const size_t needA = baseF*4 + (2*nHS + nXP)*4;    // ~789 MB: fp32 everything
  const size_t needB = baseF*4 + (2*nHS + nXP)*2;    // ~396 MB: bf16 hs + bf16 xp

  if (ws_size >= needA) {
    float* hsf = (float*)stbase;
    float* hsr = hsf + nHS;
    float* xp  = hsr + nHS;
    lstm1_kernel<float><<<256, 512, 0, stream>>>(x, wihTf, whhTf, b_f,
                                                 wihTr, whhTr, b_r, hsf, hsr);
    xp2_gemm_kernel<float, float><<<8000, 256, 0, stream>>>(hsf, hsr, wT2, b2, xp);
    lstm2_kernel<float><<<128, 512, 0, stream>>>(xp, whh2T, h2l, hc, cc, 0, TSTEPS);
  } else if (ws_size >= needB) {
    __hip_bfloat16* hsf = (__hip_bfloat16*)stbase;
    __hip_bfloat16* hsr = hsf + nHS;
    __hip_bfloat16* xp  = hsr + nHS;
    lstm1_kernel<__hip_bfloat16><<<256, 512, 0, stream>>>(x, wihTf, whhTf, b_f,
                                                          wihTr, whhTr, b_r, hsf, hsr);
    xp2_gemm_kernel<__hip_bfloat16, __hip_bfloat16><<<8000, 256, 0, stream>>>(hsf, hsr, wT2, b2, xp);
    lstm2_kernel<__hip_bfloat16><<<128, 512, 0, stream>>>(xp, whh2T, h2l, hc, cc, 0, TSTEPS);
  } else {
    // bf16 hs + time-chunked xp; pick the largest fp32 chunk that fits,
    // falling to a bf16 CH=10 chunk as the last rung (~139 MB total).
    __hip_bfloat16* hsf = (__hip_bfloat16*)stbase;
    __hip_bfloat16* hsr = hsf + nHS;
    const size_t fixed = baseF*4 + 2*nHS*2;
    int CH = 0; bool xpf32 = true;
    if      (ws_size >= fixed + (size_t)125*NB*G4*4) CH = 125;
    else if (ws_size >= fixed + (size_t) 50*NB*G4*4) CH = 50;
    else if (ws_size >= fixed + (size_t) 25*NB*G4*4) CH = 25;
    else if (ws_size >= fixed + (size_t) 10*NB*G4*4) CH = 10;
    else { CH = 10; xpf32 = false; }
    lstm1_kernel<__hip_bfloat16><<<256, 512, 0, stream>>>(x, wihTf, whhTf, b_f,
                                                          wihTr, whhTr, b_r, hsf, hsr);
    const int nch = TSTEPS / CH;
    if (xpf32) {
      float* xpc = (float*)(hsr + nHS);
      for (int ci = 0; ci < nch; ++ci) {
        const __hip_bfloat16* hf = hsf + (size_t)ci*CH*NB*HID;
        const __hip_bfloat16* hr = hsr + (size_t)ci*CH*NB*HID;
        xp2_gemm_kernel<__hip_bfloat16, float><<<CH*16, 256, 0, stream>>>(hf, hr, wT2, b2, xpc);
        lstm2_kernel<float><<<128, 512, 0, stream>>>(xpc, whh2T, h2l, hc, cc, ci*CH, CH);
      }
    } else {
      __hip_bfloat16* xpc = hsr + nHS;
      for (int ci = 0; ci < nch; ++ci) {
        const __hip_bfloat16* hf = hsf + (size_t)ci*CH*NB*HID;
        const __hip_bfloat16* hr = hsr + (size_t)ci*CH*NB*HID;
        xp2_gemm_kernel<__hip_bfloat16, __hip_bfloat16><<<CH*16, 256, 0, stream>>>(hf, hr, wT2, b2, xpc);
        lstm2_kernel<__hip_bfloat16><<<128, 512, 0, stream>>>(xpc, whh2T, h2l, hc, cc, ci*CH, CH);
      }
    }
  }
  head_kernel<<<512, 128, 0, stream>>>(h2l, W1T, b1, W2T, b2l, out);
}